// Round 9
// baseline (152.205 us; speedup 1.0000x reference)
//
#include <hip/hip_runtime.h>
#include <cstdint>
#include <cstddef>

#define N_INST 131072
#define D_EMB  512
#define ATT    128
#define NBAGS  256
#define TILE_I 32
#define LDA    520   // padded bf16 row stride (1040 B)
#define NBLK   256   // persistent blocks, 1 per CU
#define NTILES (N_INST / TILE_I)   // 4096
#define TPB    (NTILES / NBLK)     // 16 contiguous tiles per block

typedef __attribute__((ext_vector_type(8))) short  bf16x8;
typedef __attribute__((ext_vector_type(4))) float  f32x4;
typedef __attribute__((ext_vector_type(4))) unsigned short u16x4;

// raw barrier: wait own LDS ops, s_barrier, NO vmcnt drain -> HBM prefetch
// survives across phases (the __syncthreads vmcnt(0) drain was the r3-r8 wall)
#define BAR() do {                                             \
    asm volatile("s_waitcnt lgkmcnt(0)" ::: "memory");          \
    __builtin_amdgcn_s_barrier();                               \
    asm volatile("" ::: "memory");                              \
} while (0)

// ---------------- workspace layout (floats) ----------------
// [0] Z1, [1] Z2
// [16..528)     v[512]     = W_c @ w_out (folded classifier)
// [1024..1280)  e2[256]
// [1536..2048)  outer[512]
// [4096..36864) Wt bf16 [128][512] (W_a1 transposed, n-major; 65536 bf16)
// [36864..1085440)  rawr[8][256][512]  (replica-sharded bag accumulators)

__device__ inline unsigned short f2b(float f) {
    unsigned u = __builtin_bit_cast(unsigned, f);
    u += 0x7FFFu + ((u >> 16) & 1u);          // RNE
    return (unsigned short)(u >> 16);
}

__device__ inline float fast_tanh(float x) {
    float e = __expf(2.f * x);                // +inf/0 at extremes -> exact +-1
    return 1.f - 2.f / (e + 1.f);
}

// ============ prep: Wt[n][k] = bf16(W_a1[k][n]) ============
__global__ __launch_bounds__(256) void k_prep_wt(
    const float* __restrict__ Wa1, unsigned short* __restrict__ Wt)
{
    const int n = blockIdx.x;
    for (int k = threadIdx.x; k < D_EMB; k += 256)
        Wt[(size_t)n * D_EMB + k] = f2b(Wa1[(size_t)k * ATT + n]);
}

// ============ K1: persistent fused attention, vmem-free GEMM phase ==========
// 256 blocks x 512 threads (8 waves). Wave w owns n-cols [16w,16w+16); its B
// fragments (64 VGPR) are loaded ONCE. Per iteration the ONLY in-loop vmem is
// the next tile's A-prefetch (8 float4/thread), issued at the top and consumed
// at the bottom -- raw barriers keep it in flight across the whole iteration.
// Segment sums carry in registers across the block's 16 contiguous tiles.
__global__ __launch_bounds__(512, 1) void k_att1(
    const float* __restrict__ emb, const int* __restrict__ lab,
    const unsigned short* __restrict__ Wt, const float* __restrict__ ba1,
    const float* __restrict__ wo1, const float* __restrict__ bo1,
    float* __restrict__ rawr, int R, float* __restrict__ Z1)
{
    __shared__ unsigned short Ash[2][TILE_I * LDA];   // 2 x 33280 B
    __shared__ float att8[8][TILE_I];
    __shared__ float sval[TILE_I];
    __shared__ int   labs[2][TILE_I];

    const int t  = threadIdx.x;
    const int w  = t >> 6;        // 0..7: wave owns n-cols [16w, 16w+16)
    const int l  = t & 63;
    const int l4 = l & 15;
    const int h4 = l >> 4;        // 0..3
    const int n0 = 16 * w + l4;   // this lane's output column
    const size_t tile0 = (size_t)blockIdx.x * TPB;
    float* __restrict__ raw = rawr + (size_t)(blockIdx.x % R) * (NBAGS * D_EMB);

    const float ba1v = ba1[n0];
    const float wo1v = wo1[n0];

    // ---- B fragments, loaded once: 16 x bf16x8 = 64 VGPR ----
    bf16x8 bfrag[16];
    #pragma unroll
    for (int ks = 0; ks < 16; ++ks)
        bfrag[ks] = *reinterpret_cast<const bf16x8*>(
            &Wt[(size_t)n0 * D_EMB + 32 * ks + 8 * h4]);

    // ---- prologue: stage tile0 into buf 0 ----
    {
        const size_t i0 = tile0 * TILE_I;
        float4 v[8];
        #pragma unroll
        for (int j = 0; j < 8; ++j) {
            int idx = j * 512 + t;           // float4 idx in [0, 4096)
            int row = idx >> 7;              // 128 float4 per row
            int c4  = (idx & 127) * 4;
            v[j] = *reinterpret_cast<const float4*>(&emb[(i0 + row) * D_EMB + c4]);
        }
        if (t < TILE_I) labs[0][t] = lab[i0 + t];
        #pragma unroll
        for (int j = 0; j < 8; ++j) {
            int idx = j * 512 + t;
            int row = idx >> 7;
            int c4  = (idx & 127) * 4;
            u16x4 b = { f2b(v[j].x), f2b(v[j].y), f2b(v[j].z), f2b(v[j].w) };
            *reinterpret_cast<u16x4*>(&Ash[0][row * LDA + c4]) = b;
        }
    }
    BAR();

    int   cur_bag = -1;
    float a_run   = 0.f;
    float z1acc   = 0.f;
    int   p       = 0;

    for (int it = 0; it < TPB; ++it) {
        const bool hasNext = (it + 1 < TPB);
        const size_t i0n = (tile0 + it + 1) * TILE_I;

        // ---- (1) A-prefetch for next tile: the ONLY in-loop vmem ----
        float4 v[8];
        int nlab = 0;
        if (hasNext) {
            #pragma unroll
            for (int j = 0; j < 8; ++j) {
                int idx = j * 512 + t;
                int row = idx >> 7;
                int c4  = (idx & 127) * 4;
                v[j] = *reinterpret_cast<const float4*>(
                    &emb[(i0n + row) * D_EMB + c4]);
            }
            if (t < TILE_I) nlab = lab[i0n + t];
        }

        // ---- (2) score GEMM: LDS + register MFMA only, zero vmem ----
        f32x4 acc0 = {0.f,0.f,0.f,0.f}, acc1 = {0.f,0.f,0.f,0.f};
        #pragma unroll
        for (int ks = 0; ks < 16; ++ks) {
            bf16x8 a0 = *reinterpret_cast<const bf16x8*>(
                &Ash[p][(l4) * LDA + 32 * ks + 8 * h4]);
            bf16x8 a1 = *reinterpret_cast<const bf16x8*>(
                &Ash[p][(16 + l4) * LDA + 32 * ks + 8 * h4]);
            acc0 = __builtin_amdgcn_mfma_f32_16x16x32_bf16(a0, bfrag[ks], acc0, 0, 0, 0);
            acc1 = __builtin_amdgcn_mfma_f32_16x16x32_bf16(a1, bfrag[ks], acc1, 0, 0, 0);
        }

        // ---- (3) epilogue: per-wave score partials ----
        // C layout: col = l4 + 16w, row = 16rt + 4h4 + reg (validated r2)
        #pragma unroll
        for (int rt = 0; rt < 2; ++rt) {
            #pragma unroll
            for (int reg = 0; reg < 4; ++reg) {
                float pp = fast_tanh((rt ? acc1[reg] : acc0[reg]) + ba1v) * wo1v;
                pp += __shfl_xor(pp, 1);
                pp += __shfl_xor(pp, 2);
                pp += __shfl_xor(pp, 4);
                pp += __shfl_xor(pp, 8);
                if (l4 == 0) att8[w][16 * rt + 4 * h4 + reg] = pp;
            }
        }
        BAR();                                             // B1
        if (t < TILE_I) {
            float a = bo1[0];
            #pragma unroll
            for (int ww = 0; ww < 8; ++ww) a += att8[ww][t];
            float sg = 1.f / (1.f + __expf(-a));   // in (0,1): exp needs no max-sub
            float s  = __expf(sg);
            sval[t]  = s;
            float z = s;                           // lanes 0..31 of wave 0
            z += __shfl_xor(z, 1);
            z += __shfl_xor(z, 2);
            z += __shfl_xor(z, 4);
            z += __shfl_xor(z, 8);
            z += __shfl_xor(z, 16);
            if (t == 0) z1acc += z;
        }
        BAR();                                             // B2

        // ---- (4) phase 2: weighted segment sum, register carry across tiles.
        // thread t owns dim t; labels sorted -> bag ids non-decreasing.
        {
            int s0 = 0;
            while (s0 < TILE_I) {
                int bag = labs[p][s0];
                int s1 = s0 + 1;
                while (s1 < TILE_I && labs[p][s1] == bag) ++s1;
                if (bag != cur_bag) {
                    if (cur_bag >= 0)
                        atomicAdd(&raw[cur_bag * D_EMB + t], a_run);
                    a_run = 0.f;
                    cur_bag = bag;
                }
                #pragma unroll 8
                for (int ii = s0; ii < s1; ++ii) {
                    unsigned short us = Ash[p][(size_t)ii * LDA + t];
                    float e = __builtin_bit_cast(float, (unsigned)us << 16);
                    a_run = fmaf(sval[ii], e, a_run);
                }
                s0 = s1;
            }
        }
        BAR();                                             // B3: Ash[p] free

        // ---- (5) write prefetched tile into Ash[p^1] ----
        if (hasNext) {
            #pragma unroll
            for (int j = 0; j < 8; ++j) {
                int idx = j * 512 + t;
                int row = idx >> 7;
                int c4  = (idx & 127) * 4;
                u16x4 b = { f2b(v[j].x), f2b(v[j].y), f2b(v[j].z), f2b(v[j].w) };
                *reinterpret_cast<u16x4*>(&Ash[p ^ 1][row * LDA + c4]) = b;
            }
            if (t < TILE_I) labs[p ^ 1][t] = nlab;
        }
        BAR();                                             // B4: buffer ready
        p ^= 1;
    }

    if (cur_bag >= 0) atomicAdd(&raw[cur_bag * D_EMB + t], a_run);
    if (t == 0) atomicAdd(Z1, z1acc);
}

// ============ K2: replica-sum + normalize + bag-level attention ============
__global__ __launch_bounds__(128) void k_att2(
    const float* __restrict__ Wa2, const float* __restrict__ ba2,
    const float* __restrict__ wo2, const float* __restrict__ bo2,
    float* __restrict__ rawr, int R, const float* __restrict__ Z1,
    float* __restrict__ e2, float* __restrict__ Z2)
{
    __shared__ float sec[D_EMB];
    __shared__ float hh[2];
    const int b = blockIdx.x;
    const int t = threadIdx.x;
    const float zinv = 1.f / Z1[0];
    for (int d = t; d < D_EMB; d += 128) {
        float s = 0.f;
        for (int r = 0; r < R; ++r)
            s += rawr[(size_t)r * (NBAGS * D_EMB) + b * D_EMB + d];
        float v = s * zinv;
        rawr[b * D_EMB + d] = v;           // normalized into replica 0
        sec[d] = v;
    }
    __syncthreads();
    float dot = 0.f;
    #pragma unroll 8
    for (int d = 0; d < D_EMB; ++d) dot = fmaf(sec[d], Wa2[d * ATT + t], dot);
    float h = fast_tanh(dot + ba2[t]) * wo2[t];
    #pragma unroll
    for (int m = 1; m < 64; m <<= 1) h += __shfl_xor(h, m);
    if ((t & 63) == 0) hh[t >> 6] = h;
    __syncthreads();
    if (t == 0) {
        float a  = hh[0] + hh[1] + bo2[0];
        float sg = 1.f / (1.f + __expf(-a));
        float e  = __expf(sg);
        e2[b] = e;
        atomicAdd(Z2, e);
    }
}

// ============ Kv: v = W_c @ w_out ============
__global__ __launch_bounds__(256) void k_v(
    const float* __restrict__ Wc, const float* __restrict__ wout,
    float* __restrict__ v)
{
    const int t   = threadIdx.x;
    const int row = blockIdx.x * 8 + (t >> 5);
    const int l   = t & 31;
    float s = 0.f;
    #pragma unroll 4
    for (int c = l; c < 512; c += 32) s = fmaf(Wc[(size_t)row * 512 + c], wout[c], s);
    #pragma unroll
    for (int m = 1; m < 32; m <<= 1) s += __shfl_xor(s, m);
    if (l == 0) v[row] = s;
}

// ============ pool: outer_raw = sum_b e2[b] * raw0[b][:] (8 blocks) ===========
__global__ __launch_bounds__(256) void k_pool(
    const float* __restrict__ raw, const float* __restrict__ e2,
    float* __restrict__ outer)
{
    const int t  = threadIdx.x;
    const int b0 = blockIdx.x * 32;
    float o0 = 0.f, o1 = 0.f;
    for (int b = b0; b < b0 + 32; ++b) {
        float wgt = e2[b];
        float2 r = *reinterpret_cast<const float2*>(&raw[b * D_EMB + 2 * t]);
        o0 = fmaf(wgt, r.x, o0);
        o1 = fmaf(wgt, r.y, o1);
    }
    atomicAdd(&outer[2 * t], o0);
    atomicAdd(&outer[2 * t + 1], o1);
}

// ============ classifier: pred = sigmoid(outer/Z2 . v + bc . wout + bout) ====
__global__ __launch_bounds__(256) void k_cls(
    const float* __restrict__ outer, const float* __restrict__ Z2,
    const float* __restrict__ v, const float* __restrict__ bc,
    const float* __restrict__ wout, const float* __restrict__ bout,
    float* __restrict__ out)
{
    __shared__ float pp[4];
    const int t = threadIdx.x;
    const float z2inv = 1.f / Z2[0];
    float p = (outer[2 * t] * v[2 * t] + outer[2 * t + 1] * v[2 * t + 1]) * z2inv
            + bc[2 * t] * wout[2 * t] + bc[2 * t + 1] * wout[2 * t + 1];
    #pragma unroll
    for (int m = 1; m < 64; m <<= 1) p += __shfl_xor(p, m);
    if ((t & 63) == 0) pp[t >> 6] = p;
    __syncthreads();
    if (t == 0) {
        float s = pp[0] + pp[1] + pp[2] + pp[3] + bout[0];
        out[0] = 1.f / (1.f + __expf(-s));
    }
}

extern "C" void kernel_launch(void* const* d_in, const int* in_sizes, int n_in,
                              void* d_out, int out_size, void* d_ws, size_t ws_size,
                              hipStream_t stream)
{
    const float* emb  = (const float*)d_in[0];
    const int*   lab  = (const int*)d_in[1];
    const float* Wa1  = (const float*)d_in[2];
    const float* ba1  = (const float*)d_in[3];
    const float* wo1  = (const float*)d_in[4];
    const float* bo1  = (const float*)d_in[5];
    const float* Wa2  = (const float*)d_in[6];
    const float* ba2  = (const float*)d_in[7];
    const float* wo2  = (const float*)d_in[8];
    const float* bo2  = (const float*)d_in[9];
    const float* Wc   = (const float*)d_in[10];
    const float* bc   = (const float*)d_in[11];
    const float* wout = (const float*)d_in[12];
    const float* bout = (const float*)d_in[13];

    float* ws    = (float*)d_ws;
    float* Z1    = ws + 0;
    float* Z2    = ws + 1;
    float* v     = ws + 16;
    float* e2    = ws + 1024;
    float* outer = ws + 1536;
    unsigned short* Wt = (unsigned short*)(ws + 4096);
    float* rawr  = ws + 36864;

    // replica count: 8 if workspace allows (XCD-local atomics), else 1
    const size_t need8 = ((size_t)36864 + 8u * NBAGS * D_EMB) * sizeof(float);
    const int R = (ws_size >= need8) ? 8 : 1;

    // zero scalars + replica accumulators (harness does not re-poison)
    hipMemsetAsync(d_ws, 0, ((size_t)36864 + (size_t)R * NBAGS * D_EMB) * sizeof(float), stream);

    hipLaunchKernelGGL(k_prep_wt, dim3(ATT),   dim3(256), 0, stream, Wa1, Wt);
    hipLaunchKernelGGL(k_v,       dim3(64),    dim3(256), 0, stream, Wc, wout, v);
    hipLaunchKernelGGL(k_att1,    dim3(NBLK),  dim3(512), 0, stream,
                       emb, lab, Wt, ba1, wo1, bo1, rawr, R, Z1);
    hipLaunchKernelGGL(k_att2,    dim3(NBAGS), dim3(128), 0, stream,
                       Wa2, ba2, wo2, bo2, rawr, R, Z1, e2, Z2);
    hipLaunchKernelGGL(k_pool,    dim3(8),     dim3(256), 0, stream,
                       rawr, e2, outer);
    hipLaunchKernelGGL(k_cls,     dim3(1),     dim3(256), 0, stream,
                       outer, Z2, v, bc, wout, bout, (float*)d_out);
}